// Round 1
// baseline (560.280 us; speedup 1.0000x reference)
//
#include <hip/hip_runtime.h>
#include <math.h>

// x: [B=2, C=1, D=64, H=256, W=256] fp32
// out: [B=2, 16, D=64, H=256, W=256] fp32
//   even channels = sobel magnitude of x (per 2D HxW slice, zero-padded SAME)
//   odd  channels = x
//
// One thread handles 4 consecutive W pixels; computes sobel once, then emits
// 16 float4 stores (8 sobel-channel copies + 8 passthrough copies).

#define SLICES 128   // B*D = 2*64
#define Hh 256
#define Ww 256
#define W4 64        // W/4

__global__ __launch_bounds__(256) void sobel_cat_kernel(
    const float* __restrict__ in, float* __restrict__ out) {
  const int tid = blockIdx.x * blockDim.x + threadIdx.x;
  // tid layout: [n: 0..127][h: 0..255][w4: 0..63]
  const int w4 = tid & (W4 - 1);
  const int h  = (tid >> 6) & (Hh - 1);
  const int n  = tid >> 14;            // b*64 + d
  const int b  = n >> 6;
  const int d  = n & 63;
  const int w  = w4 << 2;

  const float* slice = in + (size_t)n * (Hh * Ww);

  // rows: [w-1 .. w+4], zero-padded outside the image
  float rm[6], r0[6], rp[6];

  {
    // center row always valid
    const float* rowp = slice + (size_t)h * Ww;
    float4 c = *(const float4*)(rowp + w);
    r0[1] = c.x; r0[2] = c.y; r0[3] = c.z; r0[4] = c.w;
    r0[0] = (w4 > 0)      ? rowp[w - 1] : 0.f;
    r0[5] = (w4 < W4 - 1) ? rowp[w + 4] : 0.f;
  }
  if (h > 0) {
    const float* rowp = slice + (size_t)(h - 1) * Ww;
    float4 c = *(const float4*)(rowp + w);
    rm[1] = c.x; rm[2] = c.y; rm[3] = c.z; rm[4] = c.w;
    rm[0] = (w4 > 0)      ? rowp[w - 1] : 0.f;
    rm[5] = (w4 < W4 - 1) ? rowp[w + 4] : 0.f;
  } else {
    #pragma unroll
    for (int i = 0; i < 6; ++i) rm[i] = 0.f;
  }
  if (h < Hh - 1) {
    const float* rowp = slice + (size_t)(h + 1) * Ww;
    float4 c = *(const float4*)(rowp + w);
    rp[1] = c.x; rp[2] = c.y; rp[3] = c.z; rp[4] = c.w;
    rp[0] = (w4 > 0)      ? rowp[w - 1] : 0.f;
    rp[5] = (w4 < W4 - 1) ? rowp[w + 4] : 0.f;
  } else {
    #pragma unroll
    for (int i = 0; i < 6; ++i) rp[i] = 0.f;
  }

  float sv[4], vv[4];
  #pragma unroll
  for (int i = 0; i < 4; ++i) {
    // pixel i sits at column w+i -> local index i+1; left=i, right=i+2
    float gx = (rm[i + 2] - rm[i]) + 2.f * (r0[i + 2] - r0[i]) + (rp[i + 2] - rp[i]);
    float gy = (rp[i] - rm[i]) + 2.f * (rp[i + 1] - rm[i + 1]) + (rp[i + 2] - rm[i + 2]);
    sv[i] = sqrtf(gx * gx + gy * gy);
    vv[i] = r0[i + 1];
  }
  const float4 s = make_float4(sv[0], sv[1], sv[2], sv[3]);
  const float4 v = make_float4(vv[0], vv[1], vv[2], vv[3]);

  // out slice for (b, c, d): ((b*16 + c)*64 + d) = b*1024 + c*64 + d
  float* obase = out + ((size_t)(b * 1024 + d)) * (Hh * Ww) + (size_t)h * Ww + w;
  #pragma unroll
  for (int c = 0; c < 16; ++c) {
    *(float4*)(obase + (size_t)c * (64 * Hh * Ww)) = (c & 1) ? v : s;
  }
}

extern "C" void kernel_launch(void* const* d_in, const int* in_sizes, int n_in,
                              void* d_out, int out_size, void* d_ws, size_t ws_size,
                              hipStream_t stream) {
  const float* x = (const float*)d_in[0];
  float* out = (float*)d_out;
  // total threads: 128 slices * 256 h * 64 w4 = 2,097,152
  const int total = SLICES * Hh * W4;
  const int block = 256;
  const int grid = total / block;  // 8192
  sobel_cat_kernel<<<grid, block, 0, stream>>>(x, out);
}